// Round 10
// baseline (2418.562 us; speedup 1.0000x reference)
//
#include <hip/hip_runtime.h>
#include <stdint.h>

#define VOCAB 32000
#define EMBD 512
#define HID 512
#define BATCH 32
#define SEQL 512

typedef short bf16x8 __attribute__((ext_vector_type(8)));
typedef short bf16x4 __attribute__((ext_vector_type(4)));
typedef float f32x4 __attribute__((ext_vector_type(4)));

#define AGENT __HIP_MEMORY_SCOPE_AGENT
#define RLX __ATOMIC_RELAXED

static __device__ __forceinline__ float bf2f(short u) {
  union { unsigned u; float f; } c;
  c.u = ((unsigned)(unsigned short)u) << 16;
  return c.f;
}
static __device__ __forceinline__ unsigned short f2bf(float f) {
  union { float f; unsigned u; } c;
  c.f = f;
  unsigned x = c.u;
  unsigned r = (x + 0x7fffu + ((x >> 16) & 1u)) >> 16;
  return (unsigned short)r;
}

// ---------------- f32 -> bf16 convert (8 elems/thread) ----------------
__global__ __launch_bounds__(256) void cvt_f32_bf16(
    const float* __restrict__ src, unsigned short* __restrict__ dst, int n8) {
  int i = blockIdx.x * 256 + threadIdx.x;
  if (i >= n8) return;
  const float4* s = (const float4*)src + (size_t)i * 2;
  float4 a = s[0], b = s[1];
  uint4 p;
  p.x = (unsigned)f2bf(a.x) | ((unsigned)f2bf(a.y) << 16);
  p.y = (unsigned)f2bf(a.z) | ((unsigned)f2bf(a.w) << 16);
  p.z = (unsigned)f2bf(b.x) | ((unsigned)f2bf(b.y) << 16);
  p.w = (unsigned)f2bf(b.z) | ((unsigned)f2bf(b.w) << 16);
  ((uint4*)dst)[i] = p;
}

// ---------------- gx GEMM: gx[s][d][g][b] = x[b,s,:]·W_ih[d,g,:] + b_ih ----
#define GBM 128
#define GBN 128
#define GBK 64

__global__ __launch_bounds__(256) void gemm_gx(
    const int* __restrict__ enc,                 // [B][S]
    const unsigned short* __restrict__ embb,     // [VOCAB][512] bf16
    const unsigned short* __restrict__ wih,      // [3072][512] bf16
    const float* __restrict__ b_ih,              // [3072]
    unsigned short* __restrict__ gx)             // [S][2][1536][32] bf16
{
  __shared__ __align__(16) unsigned short As[GBM * GBK];
  __shared__ __align__(16) unsigned short Bs[GBN * GBK];
  __shared__ int tokl[GBM];

  const int n0 = blockIdx.x * GBN;
  const int m0 = blockIdx.y * GBM;
  const int tid = threadIdx.x;
  if (tid < GBM) {
    int m = m0 + tid;
    tokl[tid] = enc[(m & 31) * SEQL + (m >> 5)];
  }
  __syncthreads();

  const int l = tid & 63, w = tid >> 6;
  const int wr = w >> 1, wc = w & 1;

  f32x4 acc[4][4];
  f32x4 zero = {0.f, 0.f, 0.f, 0.f};
#pragma unroll
  for (int mt = 0; mt < 4; ++mt)
#pragma unroll
    for (int nt = 0; nt < 4; ++nt) acc[mt][nt] = zero;

  for (int kt = 0; kt < 512; kt += GBK) {
#pragma unroll
    for (int it = 0; it < 4; ++it) {  // A stage
      int c = it * 256 + tid;
      int r = c >> 3, kc = c & 7;
      uint4 v = *(const uint4*)(embb + (size_t)tokl[r] * 512 + kt + kc * 8);
      unsigned off = (unsigned)(r * 128 + kc * 16); off ^= (r & 7) << 4;
      *(uint4*)((char*)As + off) = v;
    }
#pragma unroll
    for (int it = 0; it < 4; ++it) {  // B stage
      int c = it * 256 + tid;
      int r = c >> 3, kc = c & 7;
      uint4 v = *(const uint4*)(wih + (size_t)(n0 + r) * 512 + kt + kc * 8);
      unsigned off = (unsigned)(r * 128 + kc * 16); off ^= (r & 7) << 4;
      *(uint4*)((char*)Bs + off) = v;
    }
    __syncthreads();
#pragma unroll
    for (int ks = 0; ks < 2; ++ks) {
      bf16x8 af[4], bfr[4];
#pragma unroll
      for (int mt = 0; mt < 4; ++mt) {
        int r = wr * 64 + mt * 16 + (l & 15);
        unsigned off = (unsigned)(r * 128 + ks * 64 + (l >> 4) * 16);
        off ^= (r & 7) << 4;
        af[mt] = *(const bf16x8*)((char*)As + off);
      }
#pragma unroll
      for (int nt = 0; nt < 4; ++nt) {
        int r = wc * 64 + nt * 16 + (l & 15);
        unsigned off = (unsigned)(r * 128 + ks * 64 + (l >> 4) * 16);
        off ^= (r & 7) << 4;
        bfr[nt] = *(const bf16x8*)((char*)Bs + off);
      }
#pragma unroll
      for (int mt = 0; mt < 4; ++mt)
#pragma unroll
        for (int nt = 0; nt < 4; ++nt)
          acc[mt][nt] = __builtin_amdgcn_mfma_f32_16x16x32_bf16(
              af[mt], bfr[nt], acc[mt][nt], 0, 0, 0);
    }
    __syncthreads();
  }

#pragma unroll
  for (int nt = 0; nt < 4; ++nt) {
    int n = n0 + wc * 64 + nt * 16 + (l & 15);
    int d = n >= 1536 ? 1 : 0;
    int g = n - d * 1536;
    float bias = b_ih[n];
#pragma unroll
    for (int mt = 0; mt < 4; ++mt) {
      int mbase = m0 + wr * 64 + mt * 16 + (l >> 4) * 4;
      int s = mbase >> 5;
      int b = mbase & 31;
      unsigned v0 = (unsigned)f2bf(acc[mt][nt][0] + bias) |
                    ((unsigned)f2bf(acc[mt][nt][1] + bias) << 16);
      unsigned v1 = (unsigned)f2bf(acc[mt][nt][2] + bias) |
                    ((unsigned)f2bf(acc[mt][nt][3] + bias) << 16);
      size_t off = ((size_t)(s * 2 + d) * 1536 + g) * 32 + b;
      uint2 pv; pv.x = v0; pv.y = v1;
      *(uint2*)(gx + off) = pv;
    }
  }
}

// ---------------- persistent GRU scan: R8 protocol, ring-of-16 -------------
// 32 WGs = 2 dirs x 16 j-slices (JW=32), 128 thr = 2 waves (b-halves).
// All cross-WG traffic = relaxed sc1 agent atomics (only proven transport).
// Per-WAVE rings (no in-loop __syncthreads):
//   iter t: [poll 16 per-WG flags >= t] -> bulk-read h_{t-1} (256B/lane,
//   once) -> MFMA (96) -> gates -> publish h_t (4 packed u32 stores) ->
//   wave-local vmcnt(0) drain -> lane0 flag -> out stores + gx prefetch.
// Lapping-safe: wait->read->publish order (R2/R8 proof).
#define JW 32
#define NWGD 16

__global__ __launch_bounds__(128) void scan_gru(
    const unsigned short* __restrict__ gx,    // [S][2][1536][32]
    const unsigned short* __restrict__ whh,   // [2][1536][512] bf16
    const float* __restrict__ bhh,            // [2][1536]
    unsigned short* __restrict__ hbuf,        // [2][2][32][512] bf16
    unsigned* __restrict__ flags,             // [2][2][16] u32, 64B stride
    float* __restrict__ out)                  // encoded + hidden
{
  __shared__ __align__(16) unsigned short Wl[96 * 512];  // 96KB, swizzled

  const int bid = blockIdx.x;
  const int d = bid >> 4;
  const int wg = bid & 15;
  const int j0 = wg * JW;
  const int tid = threadIdx.x;
  const int l = tid & 63;
  const int w = tid >> 6;       // wave = b-half (independent ring)

  // stage W_hh slice: rows lr = gate*32 + jj -> global row gate*512+j0+jj
  for (int it = 0; it < 48; ++it) {
    int c = it * 128 + tid;      // 16B chunks; 64 per row; 6144 total
    int lr = c >> 6, kc = c & 63;
    int gate = lr >> 5, jj = lr & 31;
    uint4 v = *(const uint4*)(whh +
        (size_t)(d * 1536 + gate * 512 + j0 + jj) * 512 + kc * 8);
    unsigned off = (unsigned)(lr * 1024 + kc * 16); off ^= (lr & 7) << 4;
    *(uint4*)((char*)Wl + off) = v;
  }

  const int jl = l & 15;
  const int b0 = w * 16;
  const int brow = b0 + (l >> 4) * 4;   // first of 4 C-rows (batch) this lane owns
  float bh_r[2], bh_z[2], bh_n[2];
#pragma unroll
  for (int jt = 0; jt < 2; ++jt) {
    int jg = j0 + jt * 16 + jl;
    bh_r[jt] = bhh[d * 1536 + jg];
    bh_z[jt] = bhh[d * 1536 + 512 + jg];
    bh_n[jt] = bhh[d * 1536 + 1024 + jg];
  }

  // per-wave ring flags: [d][w][wg] at 64B stride
  unsigned* myflag = flags + ((size_t)(d * 2 + w) * NWGD + wg) * 16;
  const unsigned* fbase = flags + (size_t)(d * 2 + w) * NWGD * 16;

  float hold[2][4] = {{0.f, 0.f, 0.f, 0.f}, {0.f, 0.f, 0.f, 0.f}};

  __syncthreads();  // Wl ready (only barrier in the kernel)

  // prefetch gx for t=0
  bf16x4 gr[2], gz[2], gn[2];
  {
    size_t gb = (size_t)d * 1536 * 32;
#pragma unroll
    for (int jt = 0; jt < 2; ++jt) {
      int jg = j0 + jt * 16 + jl;
      gr[jt] = *(const bf16x4*)(gx + gb + (size_t)jg * 32 + brow);
      gz[jt] = *(const bf16x4*)(gx + gb + (size_t)(512 + jg) * 32 + brow);
      gn[jt] = *(const bf16x4*)(gx + gb + (size_t)(1024 + jg) * 32 + brow);
    }
  }

  for (int t = 0; t < SEQL; ++t) {
    f32x4 zero = {0.f, 0.f, 0.f, 0.f};
    f32x4 acc[2][3];
#pragma unroll
    for (int jt = 0; jt < 2; ++jt)
#pragma unroll
      for (int g = 0; g < 3; ++g) acc[jt][g] = zero;

    if (t > 0) {
      const unsigned tagv = (unsigned)t;
      // ---- poll 16 per-WG flags (lanes 0..15, one flag each) ----
      for (;;) {
        unsigned fv = tagv;
        if (l < NWGD)
          fv = __hip_atomic_load(fbase + (size_t)l * 16, RLX, AGENT);
        if (__ballot(fv >= tagv) == ~0ull) break;
        __builtin_amdgcn_s_sleep(1);
      }
      // ---- one-shot bulk read of h_{t-1} (untagged bf16, 256B/lane) ----
      const unsigned long long* hq = (const unsigned long long*)
          (hbuf + (size_t)(d * 2 + ((t - 1) & 1)) * 32 * 512);
      size_t qb = (size_t)(b0 + (l & 15)) * 128 + (l >> 4) * 2;  // u64 units
      union { unsigned long long q[2]; bf16x8 v; } afu[16];
#pragma unroll
      for (int ks = 0; ks < 16; ++ks) {
        afu[ks].q[0] = __hip_atomic_load(hq + qb + ks * 8, RLX, AGENT);
        afu[ks].q[1] = __hip_atomic_load(hq + qb + ks * 8 + 1, RLX, AGENT);
      }
      // ---- MFMA over K=512: 2 j-tiles x 3 gates ----
#pragma unroll
      for (int ks = 0; ks < 16; ++ks) {
        unsigned kb = (unsigned)(ks * 64 + (l >> 4) * 16);
#pragma unroll
        for (int jt = 0; jt < 2; ++jt)
#pragma unroll
          for (int g = 0; g < 3; ++g) {
            unsigned r = (unsigned)(g * 32 + jt * 16 + jl);
            bf16x8 bW = *(const bf16x8*)((char*)Wl +
                ((r * 1024 + kb) ^ ((r & 7) << 4)));
            acc[jt][g] = __builtin_amdgcn_mfma_f32_16x16x32_bf16(
                afu[ks].v, bW, acc[jt][g], 0, 0, 0);
          }
      }
    }

    // gates
#pragma unroll
    for (int jt = 0; jt < 2; ++jt)
#pragma unroll
      for (int i = 0; i < 4; ++i) {
        float ghr = acc[jt][0][i] + bh_r[jt];
        float ghz = acc[jt][1][i] + bh_z[jt];
        float ghn = acc[jt][2][i] + bh_n[jt];
        float pr = bf2f(gr[jt][i]) + ghr;
        float pz = bf2f(gz[jt][i]) + ghz;
        float r = 1.f / (1.f + __expf(-pr));
        float z = 1.f / (1.f + __expf(-pz));
        float n = tanhf(bf2f(gn[jt][i]) + r * ghn);
        hold[jt][i] = (1.f - z) * n + z * hold[jt][i];
      }

    if (t < SEQL - 1) {
      // publish h_t: pack neighbor-lane pairs -> 4 aligned u32 sc1 stores
      unsigned* hn32 = (unsigned*)(hbuf + (size_t)(d * 2 + (t & 1)) * 32 * 512);
#pragma unroll
      for (int jt = 0; jt < 2; ++jt) {
        unsigned mybf[4], pare[4];
#pragma unroll
        for (int i = 0; i < 4; ++i) mybf[i] = f2bf(hold[jt][i]);
#pragma unroll
        for (int i = 0; i < 4; ++i) {
          unsigned ot = (unsigned)__shfl_xor((int)mybf[i], 1);
          pare[i] = (jl & 1) ? (ot | (mybf[i] << 16)) : (mybf[i] | (ot << 16));
        }
        int jc2 = (j0 + jt * 16 + (jl & ~1)) >> 1;  // u32 column index
        int i0 = (jl & 1) ? 2 : 0;
        __hip_atomic_store(hn32 + (size_t)(brow + i0) * 256 + jc2, pare[i0],
                           RLX, AGENT);
        __hip_atomic_store(hn32 + (size_t)(brow + i0 + 1) * 256 + jc2,
                           pare[i0 + 1], RLX, AGENT);
      }
      // wave-local drain: h stores acked at MALL before flag store issues
      asm volatile("s_waitcnt vmcnt(0)" ::: "memory");
      if (l == 0)
        __hip_atomic_store(myflag, (unsigned)(t + 1), RLX, AGENT);
    }

    // out stores + gx prefetch: off the drain-critical path
#pragma unroll
    for (int jt = 0; jt < 2; ++jt) {
      int jg = j0 + jt * 16 + jl;
#pragma unroll
      for (int i = 0; i < 4; ++i)
        out[((size_t)(brow + i) * SEQL + t) * 1024 + d * 512 + jg] =
            hold[jt][i];
    }
    if (t == SEQL - 1) {
#pragma unroll
      for (int jt = 0; jt < 2; ++jt) {
        int jg = j0 + jt * 16 + jl;
#pragma unroll
        for (int i = 0; i < 4; ++i)
          out[(size_t)BATCH * SEQL * 1024 +
              (size_t)(d * 32 + brow + i) * 512 + jg] = hold[jt][i];
      }
    }

    if (t < SEQL - 1) {
      size_t gb = ((size_t)(t + 1) * 2 + d) * 1536 * 32;
#pragma unroll
      for (int jt = 0; jt < 2; ++jt) {
        int jg = j0 + jt * 16 + jl;
        gr[jt] = *(const bf16x4*)(gx + gb + (size_t)jg * 32 + brow);
        gz[jt] = *(const bf16x4*)(gx + gb + (size_t)(512 + jg) * 32 + brow);
        gn[jt] = *(const bf16x4*)(gx + gb + (size_t)(1024 + jg) * 32 + brow);
      }
    }
  }
}

extern "C" void kernel_launch(void* const* d_in, const int* in_sizes, int n_in,
                              void* d_out, int out_size, void* d_ws, size_t ws_size,
                              hipStream_t stream) {
  const int* enc = (const int*)d_in[0];
  const float* emb = (const float*)d_in[1];
  const float* wih = (const float*)d_in[2];
  const float* whh = (const float*)d_in[3];
  const float* bih = (const float*)d_in[4];
  const float* bhh = (const float*)d_in[5];
  float* out = (float*)d_out;

  char* ws = (char*)d_ws;
  // layout (16B aligned):
  //   [0, 4096)        flags [2][2][16] u32 @64B stride
  //   [8192, 139264)   hbuf  2*2*32*512*2 = 131072
  //   then whh_b 3145728, wih_b 3145728, emb_b 32768000, gx 100663296
  unsigned* flags = (unsigned*)ws;
  unsigned short* hbuf = (unsigned short*)(ws + 8192);
  unsigned short* whh_b = (unsigned short*)(ws + 139264);
  unsigned short* wih_b = (unsigned short*)(ws + 139264 + 3145728);
  unsigned short* emb_b = (unsigned short*)(ws + 139264 + 2 * 3145728);
  unsigned short* gx = (unsigned short*)(ws + 139264 + 2 * 3145728 + 32768000);

  hipMemsetAsync(flags, 0, 8192, stream);
  cvt_f32_bf16<<<768, 256, 0, stream>>>(whh, whh_b, 196608);
  cvt_f32_bf16<<<768, 256, 0, stream>>>(wih, wih_b, 196608);
  cvt_f32_bf16<<<8000, 256, 0, stream>>>(emb, emb_b, 2048000);
  gemm_gx<<<dim3(24, 128), 256, 0, stream>>>(enc, emb_b, wih_b, bih, gx);
  scan_gru<<<32, 128, 0, stream>>>(gx, whh_b, bhh, hbuf, flags, out);
}

// Round 11
// 2373.246 us; speedup vs baseline: 1.0191x; 1.0191x over previous
//
#include <hip/hip_runtime.h>
#include <stdint.h>

#define VOCAB 32000
#define EMBD 512
#define HID 512
#define BATCH 32
#define SEQL 512

typedef short bf16x8 __attribute__((ext_vector_type(8)));
typedef short bf16x4 __attribute__((ext_vector_type(4)));
typedef float f32x4 __attribute__((ext_vector_type(4)));

#define AGENT __HIP_MEMORY_SCOPE_AGENT
#define RLX __ATOMIC_RELAXED

static __device__ __forceinline__ float bf2f(short u) {
  union { unsigned u; float f; } c;
  c.u = ((unsigned)(unsigned short)u) << 16;
  return c.f;
}
static __device__ __forceinline__ unsigned short f2bf(float f) {
  union { float f; unsigned u; } c;
  c.f = f;
  unsigned x = c.u;
  unsigned r = (x + 0x7fffu + ((x >> 16) & 1u)) >> 16;
  return (unsigned short)r;
}

// ---------------- f32 -> bf16 convert (8 elems/thread) ----------------
__global__ __launch_bounds__(256) void cvt_f32_bf16(
    const float* __restrict__ src, unsigned short* __restrict__ dst, int n8) {
  int i = blockIdx.x * 256 + threadIdx.x;
  if (i >= n8) return;
  const float4* s = (const float4*)src + (size_t)i * 2;
  float4 a = s[0], b = s[1];
  uint4 p;
  p.x = (unsigned)f2bf(a.x) | ((unsigned)f2bf(a.y) << 16);
  p.y = (unsigned)f2bf(a.z) | ((unsigned)f2bf(a.w) << 16);
  p.z = (unsigned)f2bf(b.x) | ((unsigned)f2bf(b.y) << 16);
  p.w = (unsigned)f2bf(b.z) | ((unsigned)f2bf(b.w) << 16);
  ((uint4*)dst)[i] = p;
}

// ---------------- gx GEMM: gx[s][d][g][b] = x[b,s,:]·W_ih[d,g,:] + b_ih ----
#define GBM 128
#define GBN 128
#define GBK 64

__global__ __launch_bounds__(256) void gemm_gx(
    const int* __restrict__ enc,                 // [B][S]
    const unsigned short* __restrict__ embb,     // [VOCAB][512] bf16
    const unsigned short* __restrict__ wih,      // [3072][512] bf16
    const float* __restrict__ b_ih,              // [3072]
    unsigned short* __restrict__ gx)             // [S][2][1536][32] bf16
{
  __shared__ __align__(16) unsigned short As[GBM * GBK];
  __shared__ __align__(16) unsigned short Bs[GBN * GBK];
  __shared__ int tokl[GBM];

  const int n0 = blockIdx.x * GBN;
  const int m0 = blockIdx.y * GBM;
  const int tid = threadIdx.x;
  if (tid < GBM) {
    int m = m0 + tid;
    tokl[tid] = enc[(m & 31) * SEQL + (m >> 5)];
  }
  __syncthreads();

  const int l = tid & 63, w = tid >> 6;
  const int wr = w >> 1, wc = w & 1;

  f32x4 acc[4][4];
  f32x4 zero = {0.f, 0.f, 0.f, 0.f};
#pragma unroll
  for (int mt = 0; mt < 4; ++mt)
#pragma unroll
    for (int nt = 0; nt < 4; ++nt) acc[mt][nt] = zero;

  for (int kt = 0; kt < 512; kt += GBK) {
#pragma unroll
    for (int it = 0; it < 4; ++it) {  // A stage
      int c = it * 256 + tid;
      int r = c >> 3, kc = c & 7;
      uint4 v = *(const uint4*)(embb + (size_t)tokl[r] * 512 + kt + kc * 8);
      unsigned off = (unsigned)(r * 128 + kc * 16); off ^= (r & 7) << 4;
      *(uint4*)((char*)As + off) = v;
    }
#pragma unroll
    for (int it = 0; it < 4; ++it) {  // B stage
      int c = it * 256 + tid;
      int r = c >> 3, kc = c & 7;
      uint4 v = *(const uint4*)(wih + (size_t)(n0 + r) * 512 + kt + kc * 8);
      unsigned off = (unsigned)(r * 128 + kc * 16); off ^= (r & 7) << 4;
      *(uint4*)((char*)Bs + off) = v;
    }
    __syncthreads();
#pragma unroll
    for (int ks = 0; ks < 2; ++ks) {
      bf16x8 af[4], bfr[4];
#pragma unroll
      for (int mt = 0; mt < 4; ++mt) {
        int r = wr * 64 + mt * 16 + (l & 15);
        unsigned off = (unsigned)(r * 128 + ks * 64 + (l >> 4) * 16);
        off ^= (r & 7) << 4;
        af[mt] = *(const bf16x8*)((char*)As + off);
      }
#pragma unroll
      for (int nt = 0; nt < 4; ++nt) {
        int r = wc * 64 + nt * 16 + (l & 15);
        unsigned off = (unsigned)(r * 128 + ks * 64 + (l >> 4) * 16);
        off ^= (r & 7) << 4;
        bfr[nt] = *(const bf16x8*)((char*)Bs + off);
      }
#pragma unroll
      for (int mt = 0; mt < 4; ++mt)
#pragma unroll
        for (int nt = 0; nt < 4; ++nt)
          acc[mt][nt] = __builtin_amdgcn_mfma_f32_16x16x32_bf16(
              af[mt], bfr[nt], acc[mt][nt], 0, 0, 0);
    }
    __syncthreads();
  }

#pragma unroll
  for (int nt = 0; nt < 4; ++nt) {
    int n = n0 + wc * 64 + nt * 16 + (l & 15);
    int d = n >= 1536 ? 1 : 0;
    int g = n - d * 1536;
    float bias = b_ih[n];
#pragma unroll
    for (int mt = 0; mt < 4; ++mt) {
      int mbase = m0 + wr * 64 + mt * 16 + (l >> 4) * 4;
      int s = mbase >> 5;
      int b = mbase & 31;
      unsigned v0 = (unsigned)f2bf(acc[mt][nt][0] + bias) |
                    ((unsigned)f2bf(acc[mt][nt][1] + bias) << 16);
      unsigned v1 = (unsigned)f2bf(acc[mt][nt][2] + bias) |
                    ((unsigned)f2bf(acc[mt][nt][3] + bias) << 16);
      size_t off = ((size_t)(s * 2 + d) * 1536 + g) * 32 + b;
      uint2 pv; pv.x = v0; pv.y = v1;
      *(uint2*)(gx + off) = pv;
    }
  }
}

// ---------------- persistent GRU scan: R8 protocol + latency de-leak -------
// 64 WGs = 2 dirs x 32 j-slices (JW=16), 128 thr = 2 waves (b-halves).
// All cross-WG traffic = relaxed sc1 agent atomics (only proven transport).
// Per-WAVE rings (no in-loop __syncthreads):
//   iter t: [spec-check / poll 32 flags >= t] -> bulk-read h_{t-1} (256B/
//   lane, once) -> issue out(t-1) + gx(t+1) (retire under compute) -> MFMA
//   -> gates -> publish h_t (2 packed u32 stores) -> vmcnt(0) drain ->
//   lane0 flag -> speculative flag preload (monotonic => safe early read).
// Lapping-safe: wait->read->publish order (R2/R8 proof, unchanged).
#define JW 16

__global__ __launch_bounds__(128) void scan_gru(
    const unsigned short* __restrict__ gx,    // [S][2][1536][32]
    const unsigned short* __restrict__ whh,   // [2][1536][512] bf16
    const float* __restrict__ bhh,            // [2][1536]
    unsigned short* __restrict__ hbuf,        // [2][2][32][512] bf16
    unsigned* __restrict__ flags,             // [2][2][32] u32, 64B stride
    float* __restrict__ out)                  // encoded + hidden
{
  __shared__ __align__(16) unsigned short Wl[48 * 512];  // 48KB, swizzled

  const int bid = blockIdx.x;
  const int d = bid >> 5;
  const int wg = bid & 31;
  const int j0 = wg * JW;
  const int tid = threadIdx.x;
  const int l = tid & 63;
  const int w = tid >> 6;       // wave = b-half (independent ring)

  // stage W_hh slice: rows lr = gate*16 + jj  ->  global row gate*512+j0+jj
  for (int it = 0; it < 24; ++it) {
    int c = it * 128 + tid;      // 16B chunks; 64 per row
    int lr = c >> 6, kc = c & 63;
    int gate = lr >> 4, jj = lr & 15;
    uint4 v = *(const uint4*)(whh +
        (size_t)(d * 1536 + gate * 512 + j0 + jj) * 512 + kc * 8);
    unsigned off = (unsigned)(lr * 1024 + kc * 16); off ^= (lr & 7) << 4;
    *(uint4*)((char*)Wl + off) = v;
  }

  const int jl = l & 15;
  const int jglob = j0 + jl;
  const int b0 = w * 16;
  const int brow = b0 + (l >> 4) * 4;   // first of 4 C-rows (batch) this lane owns
  const float bh_r = bhh[d * 1536 + jglob];
  const float bh_z = bhh[d * 1536 + 512 + jglob];
  const float bh_n = bhh[d * 1536 + 1024 + jglob];

  // per-wave ring flags: [d][w][wg] at 64B stride
  unsigned* myflag = flags + ((size_t)(d * 2 + w) * 32 + wg) * 16;
  const unsigned* fbase = flags + (size_t)(d * 2 + w) * 32 * 16;

  float hold[4] = {0.f, 0.f, 0.f, 0.f};
  unsigned specv = 0;  // speculative flag preload (monotonic value)

  __syncthreads();  // Wl ready (only barrier in the kernel)

  // prefetch gx for t=0
  bf16x4 gr, gz, gn;
  {
    size_t gb = (size_t)d * 1536 * 32;
    gr = *(const bf16x4*)(gx + gb + (size_t)jglob * 32 + brow);
    gz = *(const bf16x4*)(gx + gb + (size_t)(512 + jglob) * 32 + brow);
    gn = *(const bf16x4*)(gx + gb + (size_t)(1024 + jglob) * 32 + brow);
  }

  for (int t = 0; t < SEQL; ++t) {
    f32x4 accr = {0.f, 0.f, 0.f, 0.f};
    f32x4 accz = accr, accn = accr;

    if (t > 0) {
      const unsigned tagv = (unsigned)t;
      // ---- wait: speculative check first (flags are monotonic, so an
      //      early read can only under-report; never over-report) ----
      unsigned sv = (l < 32) ? specv : 0xFFFFFFFFu;
      if (__ballot(sv >= tagv) != ~0ull) {
        for (;;) {
          unsigned fv = tagv;
          if (l < 32)
            fv = __hip_atomic_load(fbase + (size_t)l * 16, RLX, AGENT);
          if (__ballot(fv >= tagv) == ~0ull) break;
          __builtin_amdgcn_s_sleep(1);
        }
      }
      // ---- one-shot bulk read of h_{t-1} (untagged bf16, 256B/lane) ----
      const unsigned long long* hq = (const unsigned long long*)
          (hbuf + (size_t)(d * 2 + ((t - 1) & 1)) * 32 * 512);
      size_t qb = (size_t)(b0 + (l & 15)) * 128 + (l >> 4) * 2;  // u64 units
      union { unsigned long long q[2]; bf16x8 v; } afu[16];
#pragma unroll
      for (int ks = 0; ks < 16; ++ks) {
        afu[ks].q[0] = __hip_atomic_load(hq + qb + ks * 8, RLX, AGENT);
        afu[ks].q[1] = __hip_atomic_load(hq + qb + ks * 8 + 1, RLX, AGENT);
      }

      // ---- out stores for step t-1 + gx prefetch for t+1: issued here so
      //      they retire under MFMA+gates (keeps poll & drain windows clean)
#pragma unroll
      for (int i = 0; i < 4; ++i)
        out[((size_t)(brow + i) * SEQL + (t - 1)) * 1024 + d * 512 + jglob] =
            hold[i];
      bf16x4 ngr = gr, ngz = gz, ngn = gn;
      if (t < SEQL - 1) {
        size_t gb = ((size_t)(t + 1) * 2 + d) * 1536 * 32;
        ngr = *(const bf16x4*)(gx + gb + (size_t)jglob * 32 + brow);
        ngz = *(const bf16x4*)(gx + gb + (size_t)(512 + jglob) * 32 + brow);
        ngn = *(const bf16x4*)(gx + gb + (size_t)(1024 + jglob) * 32 + brow);
      }

      // ---- MFMA over K=512 ----
#pragma unroll
      for (int ks = 0; ks < 16; ++ks) {
        unsigned kb = (unsigned)(ks * 64 + (l >> 4) * 16);
        unsigned r0 = (unsigned)jl, r1 = (unsigned)(16 + jl), r2 = (unsigned)(32 + jl);
        bf16x8 bR = *(const bf16x8*)((char*)Wl + ((r0 * 1024 + kb) ^ ((r0 & 7) << 4)));
        bf16x8 bZ = *(const bf16x8*)((char*)Wl + ((r1 * 1024 + kb) ^ ((r1 & 7) << 4)));
        bf16x8 bN = *(const bf16x8*)((char*)Wl + ((r2 * 1024 + kb) ^ ((r2 & 7) << 4)));
        accr = __builtin_amdgcn_mfma_f32_16x16x32_bf16(afu[ks].v, bR, accr, 0, 0, 0);
        accz = __builtin_amdgcn_mfma_f32_16x16x32_bf16(afu[ks].v, bZ, accz, 0, 0, 0);
        accn = __builtin_amdgcn_mfma_f32_16x16x32_bf16(afu[ks].v, bN, accn, 0, 0, 0);
      }

      // gates
#pragma unroll
      for (int i = 0; i < 4; ++i) {
        float ghr = accr[i] + bh_r;
        float ghz = accz[i] + bh_z;
        float ghn = accn[i] + bh_n;
        float pr = bf2f(gr[i]) + ghr;
        float pz = bf2f(gz[i]) + ghz;
        float r = 1.f / (1.f + __expf(-pr));
        float z = 1.f / (1.f + __expf(-pz));
        float n = tanhf(bf2f(gn[i]) + r * ghn);
        hold[i] = (1.f - z) * n + z * hold[i];
      }
      gr = ngr; gz = ngz; gn = ngn;
    } else {
      // t == 0: gates with gh = b_hh only (h=0)
#pragma unroll
      for (int i = 0; i < 4; ++i) {
        float pr = bf2f(gr[i]) + bh_r;
        float pz = bf2f(gz[i]) + bh_z;
        float r = 1.f / (1.f + __expf(-pr));
        float z = 1.f / (1.f + __expf(-pz));
        float n = tanhf(bf2f(gn[i]) + r * bh_n);
        hold[i] = (1.f - z) * n;
      }
      // prefetch gx[1] (one-time; drains with the publish below)
      size_t gb = (size_t)(1 * 2 + d) * 1536 * 32;
      gr = *(const bf16x4*)(gx + gb + (size_t)jglob * 32 + brow);
      gz = *(const bf16x4*)(gx + gb + (size_t)(512 + jglob) * 32 + brow);
      gn = *(const bf16x4*)(gx + gb + (size_t)(1024 + jglob) * 32 + brow);
    }

    if (t < SEQL - 1) {
      // publish h_t: pack neighbor-lane pairs -> 2 aligned u32 sc1 stores
      unsigned* hn32 = (unsigned*)(hbuf + (size_t)(d * 2 + (t & 1)) * 32 * 512);
      unsigned mybf[4], pare[4];
#pragma unroll
      for (int i = 0; i < 4; ++i) mybf[i] = f2bf(hold[i]);
#pragma unroll
      for (int i = 0; i < 4; ++i) {
        unsigned ot = (unsigned)__shfl_xor((int)mybf[i], 1);
        pare[i] = (jl & 1) ? (ot | (mybf[i] << 16)) : (mybf[i] | (ot << 16));
      }
      int jc2 = (j0 + (jl & ~1)) >> 1;  // u32 column index
      int i0 = (jl & 1) ? 2 : 0;
      __hip_atomic_store(hn32 + (size_t)(brow + i0) * 256 + jc2, pare[i0],
                         RLX, AGENT);
      __hip_atomic_store(hn32 + (size_t)(brow + i0 + 1) * 256 + jc2,
                         pare[i0 + 1], RLX, AGENT);
      // wave-local drain: h stores acked at MALL before flag store issues
      asm volatile("s_waitcnt vmcnt(0)" ::: "memory");
      if (l == 0)
        __hip_atomic_store(myflag, (unsigned)(t + 1), RLX, AGENT);
      // speculative preload of next step's flags (monotonic => safe)
      if (l < 32)
        specv = __hip_atomic_load(fbase + (size_t)l * 16, RLX, AGENT);
    } else {
      // final step: out row 511 + hidden state
#pragma unroll
      for (int i = 0; i < 4; ++i) {
        out[((size_t)(brow + i) * SEQL + t) * 1024 + d * 512 + jglob] = hold[i];
        out[(size_t)BATCH * SEQL * 1024 +
            (size_t)(d * 32 + brow + i) * 512 + jglob] = hold[i];
      }
    }
  }
}

extern "C" void kernel_launch(void* const* d_in, const int* in_sizes, int n_in,
                              void* d_out, int out_size, void* d_ws, size_t ws_size,
                              hipStream_t stream) {
  const int* enc = (const int*)d_in[0];
  const float* emb = (const float*)d_in[1];
  const float* wih = (const float*)d_in[2];
  const float* whh = (const float*)d_in[3];
  const float* bih = (const float*)d_in[4];
  const float* bhh = (const float*)d_in[5];
  float* out = (float*)d_out;

  char* ws = (char*)d_ws;
  // layout (16B aligned):
  //   [0, 8192)        flags [2][2][32] u32 @64B stride
  //   [8192, 139264)   hbuf  2*2*32*512*2 = 131072
  //   then whh_b 3145728, wih_b 3145728, emb_b 32768000, gx 100663296
  unsigned* flags = (unsigned*)ws;
  unsigned short* hbuf = (unsigned short*)(ws + 8192);
  unsigned short* whh_b = (unsigned short*)(ws + 139264);
  unsigned short* wih_b = (unsigned short*)(ws + 139264 + 3145728);
  unsigned short* emb_b = (unsigned short*)(ws + 139264 + 2 * 3145728);
  unsigned short* gx = (unsigned short*)(ws + 139264 + 2 * 3145728 + 32768000);

  hipMemsetAsync(flags, 0, 8192, stream);
  cvt_f32_bf16<<<768, 256, 0, stream>>>(whh, whh_b, 196608);
  cvt_f32_bf16<<<768, 256, 0, stream>>>(wih, wih_b, 196608);
  cvt_f32_bf16<<<8000, 256, 0, stream>>>(emb, emb_b, 2048000);
  gemm_gx<<<dim3(24, 128), 256, 0, stream>>>(enc, emb_b, wih_b, bih, gx);
  scan_gru<<<64, 128, 0, stream>>>(gx, whh_b, bhh, hbuf, flags, out);
}

// Round 12
// 1993.024 us; speedup vs baseline: 1.2135x; 1.1908x over previous
//
#include <hip/hip_runtime.h>
#include <stdint.h>

#define VOCAB 32000
#define EMBD 512
#define HID 512
#define BATCH 32
#define SEQL 512

typedef short bf16x8 __attribute__((ext_vector_type(8)));
typedef short bf16x4 __attribute__((ext_vector_type(4)));
typedef float f32x4 __attribute__((ext_vector_type(4)));

#define AGENT __HIP_MEMORY_SCOPE_AGENT
#define RLX __ATOMIC_RELAXED

static __device__ __forceinline__ float bf2f(short u) {
  union { unsigned u; float f; } c;
  c.u = ((unsigned)(unsigned short)u) << 16;
  return c.f;
}
static __device__ __forceinline__ unsigned short f2bf(float f) {
  union { float f; unsigned u; } c;
  c.f = f;
  unsigned x = c.u;
  unsigned r = (x + 0x7fffu + ((x >> 16) & 1u)) >> 16;
  return (unsigned short)r;
}

// ---------------- f32 -> bf16 convert (8 elems/thread) ----------------
__global__ __launch_bounds__(256) void cvt_f32_bf16(
    const float* __restrict__ src, unsigned short* __restrict__ dst, int n8) {
  int i = blockIdx.x * 256 + threadIdx.x;
  if (i >= n8) return;
  const float4* s = (const float4*)src + (size_t)i * 2;
  float4 a = s[0], b = s[1];
  uint4 p;
  p.x = (unsigned)f2bf(a.x) | ((unsigned)f2bf(a.y) << 16);
  p.y = (unsigned)f2bf(a.z) | ((unsigned)f2bf(a.w) << 16);
  p.z = (unsigned)f2bf(b.x) | ((unsigned)f2bf(b.y) << 16);
  p.w = (unsigned)f2bf(b.z) | ((unsigned)f2bf(b.w) << 16);
  ((uint4*)dst)[i] = p;
}

// ---------------- gx GEMM: gx[s][d][g][b] = x[b,s,:]·W_ih[d,g,:] + b_ih ----
#define GBM 128
#define GBN 128
#define GBK 64

__global__ __launch_bounds__(256) void gemm_gx(
    const int* __restrict__ enc,                 // [B][S]
    const unsigned short* __restrict__ embb,     // [VOCAB][512] bf16
    const unsigned short* __restrict__ wih,      // [3072][512] bf16
    const float* __restrict__ b_ih,              // [3072]
    unsigned short* __restrict__ gx)             // [S][2][1536][32] bf16
{
  __shared__ __align__(16) unsigned short As[GBM * GBK];
  __shared__ __align__(16) unsigned short Bs[GBN * GBK];
  __shared__ int tokl[GBM];

  const int n0 = blockIdx.x * GBN;
  const int m0 = blockIdx.y * GBM;
  const int tid = threadIdx.x;
  if (tid < GBM) {
    int m = m0 + tid;
    tokl[tid] = enc[(m & 31) * SEQL + (m >> 5)];
  }
  __syncthreads();

  const int l = tid & 63, w = tid >> 6;
  const int wr = w >> 1, wc = w & 1;

  f32x4 acc[4][4];
  f32x4 zero = {0.f, 0.f, 0.f, 0.f};
#pragma unroll
  for (int mt = 0; mt < 4; ++mt)
#pragma unroll
    for (int nt = 0; nt < 4; ++nt) acc[mt][nt] = zero;

  for (int kt = 0; kt < 512; kt += GBK) {
#pragma unroll
    for (int it = 0; it < 4; ++it) {  // A stage
      int c = it * 256 + tid;
      int r = c >> 3, kc = c & 7;
      uint4 v = *(const uint4*)(embb + (size_t)tokl[r] * 512 + kt + kc * 8);
      unsigned off = (unsigned)(r * 128 + kc * 16); off ^= (r & 7) << 4;
      *(uint4*)((char*)As + off) = v;
    }
#pragma unroll
    for (int it = 0; it < 4; ++it) {  // B stage
      int c = it * 256 + tid;
      int r = c >> 3, kc = c & 7;
      uint4 v = *(const uint4*)(wih + (size_t)(n0 + r) * 512 + kt + kc * 8);
      unsigned off = (unsigned)(r * 128 + kc * 16); off ^= (r & 7) << 4;
      *(uint4*)((char*)Bs + off) = v;
    }
    __syncthreads();
#pragma unroll
    for (int ks = 0; ks < 2; ++ks) {
      bf16x8 af[4], bfr[4];
#pragma unroll
      for (int mt = 0; mt < 4; ++mt) {
        int r = wr * 64 + mt * 16 + (l & 15);
        unsigned off = (unsigned)(r * 128 + ks * 64 + (l >> 4) * 16);
        off ^= (r & 7) << 4;
        af[mt] = *(const bf16x8*)((char*)As + off);
      }
#pragma unroll
      for (int nt = 0; nt < 4; ++nt) {
        int r = wc * 64 + nt * 16 + (l & 15);
        unsigned off = (unsigned)(r * 128 + ks * 64 + (l >> 4) * 16);
        off ^= (r & 7) << 4;
        bfr[nt] = *(const bf16x8*)((char*)Bs + off);
      }
#pragma unroll
      for (int mt = 0; mt < 4; ++mt)
#pragma unroll
        for (int nt = 0; nt < 4; ++nt)
          acc[mt][nt] = __builtin_amdgcn_mfma_f32_16x16x32_bf16(
              af[mt], bfr[nt], acc[mt][nt], 0, 0, 0);
    }
    __syncthreads();
  }

#pragma unroll
  for (int nt = 0; nt < 4; ++nt) {
    int n = n0 + wc * 64 + nt * 16 + (l & 15);
    int d = n >= 1536 ? 1 : 0;
    int g = n - d * 1536;
    float bias = b_ih[n];
#pragma unroll
    for (int mt = 0; mt < 4; ++mt) {
      int mbase = m0 + wr * 64 + mt * 16 + (l >> 4) * 4;
      int s = mbase >> 5;
      int b = mbase & 31;
      unsigned v0 = (unsigned)f2bf(acc[mt][nt][0] + bias) |
                    ((unsigned)f2bf(acc[mt][nt][1] + bias) << 16);
      unsigned v1 = (unsigned)f2bf(acc[mt][nt][2] + bias) |
                    ((unsigned)f2bf(acc[mt][nt][3] + bias) << 16);
      size_t off = ((size_t)(s * 2 + d) * 1536 + g) * 32 + b;
      uint2 pv; pv.x = v0; pv.y = v1;
      *(uint2*)(gx + off) = pv;
    }
  }
}

// ---------------- persistent GRU scan: R8 protocol (best verified) ---------
// 64 WGs = 2 dirs x 32 j-slices (JW=16), 128 thr = 2 waves (b-halves).
// All cross-WG traffic = relaxed sc1 agent atomics (only proven transport).
// Per-WAVE rings (b-halves independent, no in-loop __syncthreads):
//   iter t: [poll 32 per-WG flags >= t] -> bulk-read h_{t-1} (untagged bf16,
//   256B/lane, once) -> MFMA -> gates -> publish h_t (2 packed u32 stores)
//   -> wave-local vmcnt(0) drain -> lane0 flag store F=t+1 -> out stores +
//   gx prefetch (off the drain path).
// Lapping-safe: wait->read->publish order; F_c >= t implies c finished
// reading h_{t-2}, so overwriting parity t&1 is safe (R2 proof).
#define JW 16

__global__ __launch_bounds__(128) void scan_gru(
    const unsigned short* __restrict__ gx,    // [S][2][1536][32]
    const unsigned short* __restrict__ whh,   // [2][1536][512] bf16
    const float* __restrict__ bhh,            // [2][1536]
    unsigned short* __restrict__ hbuf,        // [2][2][32][512] bf16
    unsigned* __restrict__ flags,             // [2][2][32] u32, 64B stride
    float* __restrict__ out)                  // encoded + hidden
{
  __shared__ __align__(16) unsigned short Wl[48 * 512];  // 48KB, swizzled

  const int bid = blockIdx.x;
  const int d = bid >> 5;
  const int wg = bid & 31;
  const int j0 = wg * JW;
  const int tid = threadIdx.x;
  const int l = tid & 63;
  const int w = tid >> 6;       // wave = b-half (independent ring)

  // stage W_hh slice: rows lr = gate*16 + jj  ->  global row gate*512+j0+jj
  for (int it = 0; it < 24; ++it) {
    int c = it * 128 + tid;      // 16B chunks; 64 per row
    int lr = c >> 6, kc = c & 63;
    int gate = lr >> 4, jj = lr & 15;
    uint4 v = *(const uint4*)(whh +
        (size_t)(d * 1536 + gate * 512 + j0 + jj) * 512 + kc * 8);
    unsigned off = (unsigned)(lr * 1024 + kc * 16); off ^= (lr & 7) << 4;
    *(uint4*)((char*)Wl + off) = v;
  }

  const int jl = l & 15;
  const int jglob = j0 + jl;
  const int b0 = w * 16;
  const int brow = b0 + (l >> 4) * 4;   // first of 4 C-rows (batch) this lane owns
  const float bh_r = bhh[d * 1536 + jglob];
  const float bh_z = bhh[d * 1536 + 512 + jglob];
  const float bh_n = bhh[d * 1536 + 1024 + jglob];

  // per-wave ring flags: [d][w][wg] at 64B stride
  unsigned* myflag = flags + ((size_t)(d * 2 + w) * 32 + wg) * 16;
  const unsigned* fbase = flags + (size_t)(d * 2 + w) * 32 * 16;

  float hold[4] = {0.f, 0.f, 0.f, 0.f};

  __syncthreads();  // Wl ready (only barrier in the kernel)

  // prefetch gx for t=0
  bf16x4 gr, gz, gn;
  {
    size_t gb = (size_t)d * 1536 * 32;
    gr = *(const bf16x4*)(gx + gb + (size_t)jglob * 32 + brow);
    gz = *(const bf16x4*)(gx + gb + (size_t)(512 + jglob) * 32 + brow);
    gn = *(const bf16x4*)(gx + gb + (size_t)(1024 + jglob) * 32 + brow);
  }

  for (int t = 0; t < SEQL; ++t) {
    f32x4 accr = {0.f, 0.f, 0.f, 0.f};
    f32x4 accz = accr, accn = accr;

    if (t > 0) {
      const unsigned tagv = (unsigned)t;
      // ---- poll 32 per-WG flags (lanes 0..31, one flag each) ----
      for (;;) {
        unsigned fv = tagv;
        if (l < 32)
          fv = __hip_atomic_load(fbase + (size_t)l * 16, RLX, AGENT);
        if (__ballot(fv >= tagv) == ~0ull) break;
        __builtin_amdgcn_s_sleep(1);
      }
      // ---- one-shot bulk read of h_{t-1} (untagged bf16, 256B/lane) ----
      const unsigned long long* hq = (const unsigned long long*)
          (hbuf + (size_t)(d * 2 + ((t - 1) & 1)) * 32 * 512);
      size_t qb = (size_t)(b0 + (l & 15)) * 128 + (l >> 4) * 2;  // u64 units
      union { unsigned long long q[2]; bf16x8 v; } afu[16];
#pragma unroll
      for (int ks = 0; ks < 16; ++ks) {
        afu[ks].q[0] = __hip_atomic_load(hq + qb + ks * 8, RLX, AGENT);
        afu[ks].q[1] = __hip_atomic_load(hq + qb + ks * 8 + 1, RLX, AGENT);
      }
#pragma unroll
      for (int ks = 0; ks < 16; ++ks) {
        unsigned kb = (unsigned)(ks * 64 + (l >> 4) * 16);
        unsigned r0 = (unsigned)jl, r1 = (unsigned)(16 + jl), r2 = (unsigned)(32 + jl);
        bf16x8 bR = *(const bf16x8*)((char*)Wl + ((r0 * 1024 + kb) ^ ((r0 & 7) << 4)));
        bf16x8 bZ = *(const bf16x8*)((char*)Wl + ((r1 * 1024 + kb) ^ ((r1 & 7) << 4)));
        bf16x8 bN = *(const bf16x8*)((char*)Wl + ((r2 * 1024 + kb) ^ ((r2 & 7) << 4)));
        accr = __builtin_amdgcn_mfma_f32_16x16x32_bf16(afu[ks].v, bR, accr, 0, 0, 0);
        accz = __builtin_amdgcn_mfma_f32_16x16x32_bf16(afu[ks].v, bZ, accz, 0, 0, 0);
        accn = __builtin_amdgcn_mfma_f32_16x16x32_bf16(afu[ks].v, bN, accn, 0, 0, 0);
      }
    }

    // gates
#pragma unroll
    for (int i = 0; i < 4; ++i) {
      float ghr = accr[i] + bh_r;
      float ghz = accz[i] + bh_z;
      float ghn = accn[i] + bh_n;
      float pr = bf2f(gr[i]) + ghr;
      float pz = bf2f(gz[i]) + ghz;
      float r = 1.f / (1.f + __expf(-pr));
      float z = 1.f / (1.f + __expf(-pz));
      float n = tanhf(bf2f(gn[i]) + r * ghn);
      hold[i] = (1.f - z) * n + z * hold[i];
    }

    if (t < SEQL - 1) {
      // publish h_t: pack neighbor-lane pairs -> 2 aligned u32 sc1 stores
      unsigned* hn32 = (unsigned*)(hbuf + (size_t)(d * 2 + (t & 1)) * 32 * 512);
      unsigned mybf[4], pare[4];
#pragma unroll
      for (int i = 0; i < 4; ++i) mybf[i] = f2bf(hold[i]);
#pragma unroll
      for (int i = 0; i < 4; ++i) {
        unsigned ot = (unsigned)__shfl_xor((int)mybf[i], 1);
        pare[i] = (jl & 1) ? (ot | (mybf[i] << 16)) : (mybf[i] | (ot << 16));
      }
      int jc2 = (j0 + (jl & ~1)) >> 1;  // u32 column index
      int i0 = (jl & 1) ? 2 : 0;
      __hip_atomic_store(hn32 + (size_t)(brow + i0) * 256 + jc2, pare[i0],
                         RLX, AGENT);
      __hip_atomic_store(hn32 + (size_t)(brow + i0 + 1) * 256 + jc2,
                         pare[i0 + 1], RLX, AGENT);
      // wave-local drain: h stores acked at MALL before flag store issues
      asm volatile("s_waitcnt vmcnt(0)" ::: "memory");
      if (l == 0)
        __hip_atomic_store(myflag, (unsigned)(t + 1), RLX, AGENT);
    }

    // out stores + gx prefetch: off the drain-critical path
#pragma unroll
    for (int i = 0; i < 4; ++i)
      out[((size_t)(brow + i) * SEQL + t) * 1024 + d * 512 + jglob] = hold[i];
    if (t == SEQL - 1) {
#pragma unroll
      for (int i = 0; i < 4; ++i)
        out[(size_t)BATCH * SEQL * 1024 +
            (size_t)(d * 32 + brow + i) * 512 + jglob] = hold[i];
    }

    if (t < SEQL - 1) {
      size_t gb = ((size_t)(t + 1) * 2 + d) * 1536 * 32;
      gr = *(const bf16x4*)(gx + gb + (size_t)jglob * 32 + brow);
      gz = *(const bf16x4*)(gx + gb + (size_t)(512 + jglob) * 32 + brow);
      gn = *(const bf16x4*)(gx + gb + (size_t)(1024 + jglob) * 32 + brow);
    }
  }
}

extern "C" void kernel_launch(void* const* d_in, const int* in_sizes, int n_in,
                              void* d_out, int out_size, void* d_ws, size_t ws_size,
                              hipStream_t stream) {
  const int* enc = (const int*)d_in[0];
  const float* emb = (const float*)d_in[1];
  const float* wih = (const float*)d_in[2];
  const float* whh = (const float*)d_in[3];
  const float* bih = (const float*)d_in[4];
  const float* bhh = (const float*)d_in[5];
  float* out = (float*)d_out;

  char* ws = (char*)d_ws;
  // layout (16B aligned):
  //   [0, 8192)        flags [2][2][32] u32 @64B stride
  //   [8192, 139264)   hbuf  2*2*32*512*2 = 131072
  //   then whh_b 3145728, wih_b 3145728, emb_b 32768000, gx 100663296
  unsigned* flags = (unsigned*)ws;
  unsigned short* hbuf = (unsigned short*)(ws + 8192);
  unsigned short* whh_b = (unsigned short*)(ws + 139264);
  unsigned short* wih_b = (unsigned short*)(ws + 139264 + 3145728);
  unsigned short* emb_b = (unsigned short*)(ws + 139264 + 2 * 3145728);
  unsigned short* gx = (unsigned short*)(ws + 139264 + 2 * 3145728 + 32768000);

  hipMemsetAsync(flags, 0, 8192, stream);
  cvt_f32_bf16<<<768, 256, 0, stream>>>(whh, whh_b, 196608);
  cvt_f32_bf16<<<768, 256, 0, stream>>>(wih, wih_b, 196608);
  cvt_f32_bf16<<<8000, 256, 0, stream>>>(emb, emb_b, 2048000);
  gemm_gx<<<dim3(24, 128), 256, 0, stream>>>(enc, emb_b, wih_b, bih, gx);
  scan_gru<<<64, 128, 0, stream>>>(gx, whh_b, bhh, hbuf, flags, out);
}